// Round 7
// baseline (1847.557 us; speedup 1.0000x reference)
//
#include <hip/hip_runtime.h>
#include <math.h>

// Problem constants
#define BB 32
#define TT 512
#define INF_ 128
#define HH 256
#define H3 768
#define NHEADS 4
#define HDIM 64

typedef _Float16 half_t;
typedef half_t half2_t __attribute__((ext_vector_type(2)));
typedef half_t half4_t __attribute__((ext_vector_type(4)));
typedef half_t f16x8 __attribute__((ext_vector_type(8)));
typedef float f32x4 __attribute__((ext_vector_type(4)));

#if defined(__has_builtin)
#if __has_builtin(__builtin_amdgcn_fdot2)
#define FDOT2(a, b, c) __builtin_amdgcn_fdot2((a), (b), (c), false)
#endif
#endif
#ifndef FDOT2
#define FDOT2(a, b, c) fmaf((float)(a).x, (float)(b).x, fmaf((float)(a).y, (float)(b).y, (c)))
#endif

#define BCH(x) __builtin_bit_cast(half2_t, x)

// ---------------- wave helpers (wave = 64 on CDNA) ----------------
__device__ __forceinline__ float wsum(float v) {
#pragma unroll
  for (int o = 32; o > 0; o >>= 1) v += __shfl_xor(v, o, 64);
  return v;
}
__device__ __forceinline__ float wmax(float v) {
#pragma unroll
  for (int o = 32; o > 0; o >>= 1) v = fmaxf(v, __shfl_xor(v, o, 64));
  return v;
}

// ---------------- fp32 -> f16 cast (n % 1024 == 0) ----------------
__global__ void castk(const float* __restrict__ s, half_t* __restrict__ d, int n) {
  int i = (blockIdx.x * 256 + threadIdx.x) * 4;
  if (i < n) {
    float4 v = *(const float4*)(s + i);
    half4_t o = {(half_t)v.x, (half_t)v.y, (half_t)v.z, (half_t)v.w};
    *(half4_t*)(d + i) = o;
  }
}

__device__ __forceinline__ f16x8 pk16(float4 a, float4 b) {
  return f16x8{(half_t)a.x, (half_t)a.y, (half_t)a.z, (half_t)a.w,
               (half_t)b.x, (half_t)b.y, (half_t)b.z, (half_t)b.w};
}

// ---------------- MFMA f16 GEMM: C[M,N] = A[M,K] * B[N,K]^T + bias -------
__global__ __launch_bounds__(256) void gemm_f16(
    const half_t* __restrict__ A, const half_t* __restrict__ B,
    const float* __restrict__ bias, float* __restrict__ C,
    int M, int N, int K) {
  __shared__ __align__(16) half_t As[128][40];
  __shared__ __align__(16) half_t Bs[64][40];
  const int tid = threadIdx.x;
  const int wave = tid >> 6, lane = tid & 63;
  const int m0 = blockIdx.y * 128, n0 = blockIdx.x * 64;
  const int mrow = lane & 15, quad = lane >> 4;
  f32x4 acc00 = {0.f, 0.f, 0.f, 0.f}, acc01 = acc00, acc02 = acc00, acc03 = acc00;
  f32x4 acc10 = acc00, acc11 = acc00, acc12 = acc00, acc13 = acc00;
  for (int k0 = 0; k0 < K; k0 += 32) {
    __syncthreads();  // previous iter's fragments consumed
#pragma unroll
    for (int u = 0; u < 2; ++u) {  // stage A: 128 rows x 32 halfs
      int idx = tid + u * 256;
      int row = idx >> 2, seg = idx & 3;
      *(f16x8*)&As[row][seg * 8] =
          *(const f16x8*)&A[(size_t)(m0 + row) * K + k0 + seg * 8];
    }
    {  // stage B: 64 rows x 32 halfs
      int row = tid >> 2, seg = tid & 3;
      *(f16x8*)&Bs[row][seg * 8] =
          *(const f16x8*)&B[(size_t)(n0 + row) * K + k0 + seg * 8];
    }
    __syncthreads();
    f16x8 af0 = *(const f16x8*)&As[wave * 32 + mrow][quad * 8];
    f16x8 af1 = *(const f16x8*)&As[wave * 32 + 16 + mrow][quad * 8];
    f16x8 bf0 = *(const f16x8*)&Bs[mrow][quad * 8];
    f16x8 bf1 = *(const f16x8*)&Bs[16 + mrow][quad * 8];
    f16x8 bf2 = *(const f16x8*)&Bs[32 + mrow][quad * 8];
    f16x8 bf3 = *(const f16x8*)&Bs[48 + mrow][quad * 8];
    acc00 = __builtin_amdgcn_mfma_f32_16x16x32_f16(af0, bf0, acc00, 0, 0, 0);
    acc01 = __builtin_amdgcn_mfma_f32_16x16x32_f16(af0, bf1, acc01, 0, 0, 0);
    acc02 = __builtin_amdgcn_mfma_f32_16x16x32_f16(af0, bf2, acc02, 0, 0, 0);
    acc03 = __builtin_amdgcn_mfma_f32_16x16x32_f16(af0, bf3, acc03, 0, 0, 0);
    acc10 = __builtin_amdgcn_mfma_f32_16x16x32_f16(af1, bf0, acc10, 0, 0, 0);
    acc11 = __builtin_amdgcn_mfma_f32_16x16x32_f16(af1, bf1, acc11, 0, 0, 0);
    acc12 = __builtin_amdgcn_mfma_f32_16x16x32_f16(af1, bf2, acc12, 0, 0, 0);
    acc13 = __builtin_amdgcn_mfma_f32_16x16x32_f16(af1, bf3, acc13, 0, 0, 0);
  }
  float bv0 = bias ? bias[n0 + mrow] : 0.f;
  float bv1 = bias ? bias[n0 + 16 + mrow] : 0.f;
  float bv2 = bias ? bias[n0 + 32 + mrow] : 0.f;
  float bv3 = bias ? bias[n0 + 48 + mrow] : 0.f;
  const int rb = m0 + wave * 32 + quad * 4;
#pragma unroll
  for (int r = 0; r < 4; ++r) {
    float* c0 = C + (size_t)(rb + r) * N + n0;
    c0[mrow] = acc00[r] + bv0;
    c0[16 + mrow] = acc01[r] + bv1;
    c0[32 + mrow] = acc02[r] + bv2;
    c0[48 + mrow] = acc03[r] + bv3;
    float* c1 = C + (size_t)(rb + 16 + r) * N + n0;
    c1[mrow] = acc10[r] + bv0;
    c1[16 + mrow] = acc11[r] + bv1;
    c1[32 + mrow] = acc12[r] + bv2;
    c1[48 + mrow] = acc13[r] + bv3;
  }
}

// ---------------- GRU recurrence: 4-way k-split, spill-free weights -------
// R6 post-mortem: allocator refuses >128 arch-VGPRs here (VGPR_Count=128
// at every config tried); with 192 half2 weights/thread, ~90 overflow to
// AGPR/scratch -> ~300 extra VALU inst/wave/step (accvgpr_read / reload),
// measured as active-CU VALUBusy 66% with only ~230 real insts.
// R7: thread (j, kh=tid&3) owns k in [64kh, 64kh+64) of all 3 gates for
// unit j -> 96 half2 weights/thread + ~25 working regs < 128 cap. 1024
// threads, partial sums reduced via __shfl_xor 1,2 (quad-local -> DPP).
// h[kh-quarter] read as 8 ds_read_b128; quarters padded to 144 B so the 4
// distinct wave addresses hit different banks. One barrier/step.
#define LDW(g, p, a, b, i)                             \
  {                                                    \
    float4 v = (p)[i];                                 \
    g##a = half2_t{(half_t)v.x, (half_t)v.y};          \
    g##b = half2_t{(half_t)v.z, (half_t)v.w};          \
  }
#define LDW16(g, p)                                                        \
  LDW(g, p, 0, 1, 0) LDW(g, p, 2, 3, 1) LDW(g, p, 4, 5, 2)                 \
  LDW(g, p, 6, 7, 3) LDW(g, p, 8, 9, 4) LDW(g, p, 10, 11, 5)               \
  LDW(g, p, 12, 13, 6) LDW(g, p, 14, 15, 7) LDW(g, p, 16, 17, 8)           \
  LDW(g, p, 18, 19, 9) LDW(g, p, 20, 21, 10) LDW(g, p, 22, 23, 11)         \
  LDW(g, p, 24, 25, 12) LDW(g, p, 26, 27, 13) LDW(g, p, 28, 29, 14)        \
  LDW(g, p, 30, 31, 15)

#define DECL32(g)                                                          \
  half2_t g##0, g##1, g##2, g##3, g##4, g##5, g##6, g##7, g##8, g##9,      \
      g##10, g##11, g##12, g##13, g##14, g##15, g##16, g##17, g##18,       \
      g##19, g##20, g##21, g##22, g##23, g##24, g##25, g##26, g##27,       \
      g##28, g##29, g##30, g##31;

// one 8-dim chunk (4 half2): r,z,n all from registers
#define CH4(c, a0, a1, a2, a3)                                             \
  {                                                                        \
    float4 v = hp4[c];                                                     \
    half2_t t0 = BCH(v.x), t1 = BCH(v.y), t2 = BCH(v.z), t3 = BCH(v.w);    \
    ar = FDOT2(wr##a0, t0, ar); az = FDOT2(wz##a0, t0, az); an = FDOT2(wn##a0, t0, an); \
    ar = FDOT2(wr##a1, t1, ar); az = FDOT2(wz##a1, t1, az); an = FDOT2(wn##a1, t1, an); \
    ar = FDOT2(wr##a2, t2, ar); az = FDOT2(wz##a2, t2, az); an = FDOT2(wn##a2, t2, an); \
    ar = FDOT2(wr##a3, t3, ar); az = FDOT2(wz##a3, t3, az); an = FDOT2(wn##a3, t3, an); \
  }

__global__ __launch_bounds__(1024, 4) void gru_layer(
    const float* __restrict__ xp, const float* __restrict__ Whh,
    const float* __restrict__ bhh, float* __restrict__ out,
    half_t* __restrict__ out16) {
  __shared__ __align__(16) half_t hs[2][4][72];  // kh-quarters, 144 B pitch
  const int tid = threadIdx.x;
  const int kh = tid & 3, j = tid >> 2;
  const int b = blockIdx.x;
  const bool wf32 = (out != nullptr);  // uniform: layer 0 skips fp32 h-store
  DECL32(wr)
  DECL32(wz)
  DECL32(wn)
  {
    const float4* pr = (const float4*)(Whh + (size_t)j * HH + kh * 64);
    const float4* pz = (const float4*)(Whh + (size_t)(HH + j) * HH + kh * 64);
    const float4* pn = (const float4*)(Whh + (size_t)(2 * HH + j) * HH + kh * 64);
    LDW16(wr, pr)
    LDW16(wz, pz)
    LDW16(wn, pn)
  }
  const float br = bhh[j], bz = bhh[HH + j], bn = bhh[2 * HH + j];
  for (int i = tid; i < 288; i += 1024) ((unsigned*)hs)[i] = 0u;
  __syncthreads();
  float hprev = 0.f;
  const float* xrow = xp + (size_t)b * TT * H3;
  float* orow = out + (size_t)b * TT * HH;
  half_t* orow16 = out16 + (size_t)b * TT * HH;
  for (int t = 0; t < TT; ++t) {
    float xr = xrow[j], xz = xrow[HH + j], xn = xrow[2 * HH + j];
    const float4* hp4 = (const float4*)&hs[t & 1][kh][0];
    float ar = 0.f, az = 0.f, an = 0.f;
    CH4(0, 0, 1, 2, 3)
    CH4(1, 4, 5, 6, 7)
    CH4(2, 8, 9, 10, 11)
    CH4(3, 12, 13, 14, 15)
    CH4(4, 16, 17, 18, 19)
    CH4(5, 20, 21, 22, 23)
    CH4(6, 24, 25, 26, 27)
    CH4(7, 28, 29, 30, 31)
    ar += __shfl_xor(ar, 1); ar += __shfl_xor(ar, 2);
    az += __shfl_xor(az, 1); az += __shfl_xor(az, 2);
    an += __shfl_xor(an, 1); an += __shfl_xor(an, 2);
    float rg = 1.f / (1.f + __expf(-(xr + ar + br)));
    float zg = 1.f / (1.f + __expf(-(xz + az + bz)));
    float ng = 2.f / (1.f + __expf(-2.f * (xn + rg * (an + bn)))) - 1.f;  // tanh, inf-safe
    float hnew = (1.f - zg) * ng + zg * hprev;
    hprev = hnew;
    if (kh == 0) {
      hs[(t + 1) & 1][j >> 6][j & 63] = (half_t)hnew;
      orow16[j] = (half_t)hnew;
      if (wf32) orow[j] = hnew;
    }
    __syncthreads();
    xrow += H3;
    orow += HH;
    orow16 += HH;
  }
}

// ---------------- gat_W transpose -> f16: [4,256,64] -> [256 cols][256 k] --
__global__ void gat_wt(const float* __restrict__ W, half_t* __restrict__ Wt) {
  int idx = blockIdx.x * 256 + threadIdx.x;  // [0, 65536)
  int col = idx >> 8, k = idx & 255;
  Wt[idx] = (half_t)W[((size_t)((col >> 6) * HH + k)) * HDIM + (col & 63)];
}

// ---------------- GAT f_src/f_dst ----------------
__global__ void gat_fsd(const float* __restrict__ hgat, const float* __restrict__ a,
                        float* __restrict__ fsrc, float* __restrict__ fdst) {
  int b = blockIdx.x, hd = blockIdx.y, t = threadIdx.x;  // block 512
  const float* hp = hgat + ((size_t)(b * TT + t)) * HH + hd * HDIM;
  const float* ap = a + hd * 2 * HDIM;
  float fs = 0.f, fd = 0.f;
#pragma unroll 4
  for (int d = 0; d < HDIM; ++d) {
    float hv = hp[d];
    fs += hv * ap[d];
    fd += hv * ap[HDIM + d];
  }
  fsrc[(b * NHEADS + hd) * TT + t] = fs;
  fdst[(b * NHEADS + hd) * TT + t] = fd;
}

// ---------------- GAT flash attention (MFMA PV) ---------------------------
// Block = 64 q rows (grid 8 x 4 hd x 32 b), 4 waves x 16 q. Scores are
// rank-1 (fi + fd[j]) -> softmax on VALU, lane owns q=lane&15, j-range
// quad*32..+32. P stored f16 in LDS [q][j]; PV = P[16,128] @ H^T[64,128]^T
// on the matrix pipe using the gemm_f16 fragment conventions (A-frag
// [m=lane&15][k=(lane>>4)*8+i], C row=(lane>>4)*4+r col=lane&15).
__global__ __launch_bounds__(256) void gat_attn(
    const float* __restrict__ hgat, const float* __restrict__ fsrc,
    const float* __restrict__ fdst, float* __restrict__ out) {
  __shared__ __align__(16) half_t Htt[64][136];     // H^T per j-tile
  __shared__ __align__(16) half_t Ps[4][16][136];   // per-wave P (f16)
  __shared__ __align__(16) float fd[128];
  const int tid = threadIdx.x, wave = tid >> 6, lane = tid & 63;
  const int mrow = lane & 15, quad = lane >> 4;
  const int hd = blockIdx.y, b = blockIdx.z;
  const int q0 = blockIdx.x * 64;
  const float fi = fsrc[(size_t)(b * NHEADS + hd) * TT + q0 + wave * 16 + mrow];
  const float* fdp = fdst + (size_t)(b * NHEADS + hd) * TT;
  float m = -1e30f, l = 0.f;
  f32x4 o[4];
#pragma unroll
  for (int n = 0; n < 4; ++n) o[n] = f32x4{0.f, 0.f, 0.f, 0.f};
  for (int jt = 0; jt < TT; jt += 128) {
#pragma unroll
    for (int u = 0; u < 4; ++u) {  // stage H^T: Htt[d][j] (f16)
      int idx = tid + u * 256;
      int j = idx >> 3, s = (idx & 7) * 8;
      const float* hp = hgat + (size_t)(b * TT + jt + j) * HH + hd * HDIM + s;
      float4 ha = *(const float4*)hp, hb = *(const float4*)(hp + 4);
      Htt[s + 0][j] = (half_t)ha.x; Htt[s + 1][j] = (half_t)ha.y;
      Htt[s + 2][j] = (half_t)ha.z; Htt[s + 3][j] = (half_t)ha.w;
      Htt[s + 4][j] = (half_t)hb.x; Htt[s + 5][j] = (half_t)hb.y;
      Htt[s + 6][j] = (half_t)hb.z; Htt[s + 7][j] = (half_t)hb.w;
    }
    if (tid < 32) *(float4*)&fd[tid * 4] = *(const float4*)&fdp[jt + tid * 4];
    __syncthreads();
    float p[32];
    float mx = -1e30f;
#pragma unroll
    for (int g = 0; g < 8; ++g) {
      float4 f4 = *(const float4*)&fd[quad * 32 + g * 4];
      float e0 = fi + f4.x; e0 = (e0 > 0.f) ? e0 : 0.2f * e0;
      float e1 = fi + f4.y; e1 = (e1 > 0.f) ? e1 : 0.2f * e1;
      float e2 = fi + f4.z; e2 = (e2 > 0.f) ? e2 : 0.2f * e2;
      float e3 = fi + f4.w; e3 = (e3 > 0.f) ? e3 : 0.2f * e3;
      p[g * 4 + 0] = e0; p[g * 4 + 1] = e1; p[g * 4 + 2] = e2; p[g * 4 + 3] = e3;
      mx = fmaxf(mx, fmaxf(fmaxf(e0, e1), fmaxf(e2, e3)));
    }
    mx = fmaxf(mx, __shfl_xor(mx, 16, 64));  // reduce over the 4 j-groups
    mx = fmaxf(mx, __shfl_xor(mx, 32, 64));
    float mn = fmaxf(m, mx);
    float corr = __expf(m - mn);
    m = mn;
    float ls = 0.f;
#pragma unroll
    for (int i = 0; i < 32; ++i) { p[i] = __expf(p[i] - mn); ls += p[i]; }
    ls += __shfl_xor(ls, 16, 64);
    ls += __shfl_xor(ls, 32, 64);
    l = l * corr + ls;
    float cr[4];  // corr for PV acc rows q' = quad*4+r (held by lane q')
#pragma unroll
    for (int r = 0; r < 4; ++r) cr[r] = __shfl(corr, quad * 4 + r, 64);
#pragma unroll
    for (int n = 0; n < 4; ++n) {
      o[n][0] *= cr[0]; o[n][1] *= cr[1]; o[n][2] *= cr[2]; o[n][3] *= cr[3];
    }
#pragma unroll
    for (int s8 = 0; s8 < 4; ++s8) {  // P f16 -> LDS [q][j]
      f16x8 pkv = {(half_t)p[s8 * 8 + 0], (half_t)p[s8 * 8 + 1],
                   (half_t)p[s8 * 8 + 2], (half_t)p[s8 * 8 + 3],
                   (half_t)p[s8 * 8 + 4], (half_t)p[s8 * 8 + 5],
                   (half_t)p[s8 * 8 + 6], (half_t)p[s8 * 8 + 7]};
      *(f16x8*)&Ps[wave][mrow][quad * 32 + s8 * 8] = pkv;
    }
    __syncthreads();
    f16x8 pa0 = *(const f16x8*)&Ps[wave][mrow][0 * 32 + quad * 8];
    f16x8 pa1 = *(const f16x8*)&Ps[wave][mrow][1 * 32 + quad * 8];
    f16x8 pa2 = *(const f16x8*)&Ps[wave][mrow][2 * 32 + quad * 8];
    f16x8 pa3 = *(const f16x8*)&Ps[wave][mrow][3 * 32 + quad * 8];
#pragma unroll
    for (int n = 0; n < 4; ++n) {
      f16x8 vb0 = *(const f16x8*)&Htt[n * 16 + mrow][0 * 32 + quad * 8];
      f16x8 vb1 = *(const f16x8*)&Htt[n * 16 + mrow][1 * 32 + quad * 8];
      f16x8 vb2 = *(const f16x8*)&Htt[n * 16 + mrow][2 * 32 + quad * 8];
      f16x8 vb3 = *(const f16x8*)&Htt[n * 16 + mrow][3 * 32 + quad * 8];
      o[n] = __builtin_amdgcn_mfma_f32_16x16x32_f16(pa0, vb0, o[n], 0, 0, 0);
      o[n] = __builtin_amdgcn_mfma_f32_16x16x32_f16(pa1, vb1, o[n], 0, 0, 0);
      o[n] = __builtin_amdgcn_mfma_f32_16x16x32_f16(pa2, vb2, o[n], 0, 0, 0);
      o[n] = __builtin_amdgcn_mfma_f32_16x16x32_f16(pa3, vb3, o[n], 0, 0, 0);
    }
    __syncthreads();  // before next tile's staging overwrites Htt
  }
  float lr[4];
#pragma unroll
  for (int r = 0; r < 4; ++r) lr[r] = __shfl(l, quad * 4 + r, 64);
#pragma unroll
  for (int n = 0; n < 4; ++n)
#pragma unroll
    for (int r = 0; r < 4; ++r)
      out[(size_t)(b * TT + q0 + wave * 16 + quad * 4 + r) * HH + hd * HDIM +
          n * 16 + mrow] = o[n][r] / lr[r];
}

// ---------------- residual + LayerNorm (f16 output for MFMA GEMM) ---------
__global__ __launch_bounds__(256) void ln_res(
    const float* __restrict__ g, const float* __restrict__ gat,
    const float* __restrict__ gamma, const float* __restrict__ beta,
    half_t* __restrict__ y16) {
  int wave = threadIdx.x >> 6, lane = threadIdx.x & 63;
  size_t n = (size_t)blockIdx.x * 4 + wave;
  float4 v = ((const float4*)(g + n * HH))[lane];
  float4 w = ((const float4*)(gat + n * HH))[lane];
  v.x += w.x; v.y += w.y; v.z += w.z; v.w += w.w;
  float mu = wsum(v.x + v.y + v.z + v.w) * (1.f / 256.f);
  float dx = v.x - mu, dy = v.y - mu, dz = v.z - mu, dw = v.w - mu;
  float var = wsum(dx * dx + dy * dy + dz * dz + dw * dw) * (1.f / 256.f);
  float rstd = rsqrtf(var + 1e-5f);
  float4 gm = ((const float4*)gamma)[lane];
  float4 bt = ((const float4*)beta)[lane];
  half4_t o = {(half_t)(dx * rstd * gm.x + bt.x), (half_t)(dy * rstd * gm.y + bt.y),
               (half_t)(dz * rstd * gm.z + bt.z), (half_t)(dw * rstd * gm.w + bt.w)};
  ((half4_t*)(y16 + n * HH))[lane] = o;
}

// ---------------- MHA flash attention (MFMA QK + PV, f16 ctx output) ------
// Block = 64 q (grid 8 x 4 hd x 32 b), 4 waves x 16 q. QK^T and PV on the
// matrix pipe; online softmax on S in C-layout (row q=(lane>>4)*4+r, col
// j=n*16+(lane&15)), j-reduce = per-lane over 8 accs + shfl_xor 1,2,4,8.
__global__ __launch_bounds__(256) void mha_attn(const float* __restrict__ qkv,
                                                half_t* __restrict__ ctx16) {
  __shared__ __align__(16) half_t Qs[64][72];
  __shared__ __align__(16) half_t Ks[128][72];
  __shared__ __align__(16) half_t Vt[64][136];
  __shared__ __align__(16) half_t Ps[4][16][136];
  const int tid = threadIdx.x, wave = tid >> 6, lane = tid & 63;
  const int mrow = lane & 15, quad = lane >> 4;
  const int hd = blockIdx.y, b = blockIdx.z;
  const int q0 = blockIdx.x * 64;
  {  // stage Q: 64 q x 64 d -> f16
    int r = tid >> 2, s = (tid & 3) * 16;
    const float* src = qkv + (size_t)(b * TT + q0 + r) * H3 + hd * HDIM + s;
    float4 a = *(const float4*)src, b4 = *(const float4*)(src + 4);
    float4 c = *(const float4*)(src + 8), d4 = *(const float4*)(src + 12);
    *(f16x8*)&Qs[r][s] = pk16(a, b4);
    *(f16x8*)&Qs[r][s + 8] = pk16(c, d4);
  }
  __syncthreads();
  f16x8 qa0 = *(const f16x8*)&Qs[wave * 16 + mrow][quad * 8];
  f16x8 qa1 = *(const f16x8*)&Qs[wave * 16 + mrow][32 + quad * 8];
  float m[4] = {-1e30f, -1e30f, -1e30f, -1e30f};
  float l[4] = {0.f, 0.f, 0.f, 0.f};
  f32x4 o[4];
#pragma unroll
  for (int n = 0; n < 4; ++n) o[n] = f32x4{0.f, 0.f, 0.f, 0.f};
  for (int jt = 0; jt < TT; jt += 128) {
#pragma unroll
    for (int u = 0; u < 4; ++u) {  // stage K [j][d] and V^T [d][j]
      int idx = tid + u * 256;
      int j = idx >> 3, s = (idx & 7) * 8;
      const float* kp = qkv + (size_t)(b * TT + jt + j) * H3 + HH + hd * HDIM + s;
      float4 ka = *(const float4*)kp, kb = *(const float4*)(kp + 4);
      *(f16x8*)&Ks[j][s] = pk16(ka, kb);
      const float* vp = kp + HH;
      float4 va = *(const float4*)vp, vb = *(const float4*)(vp + 4);
      Vt[s + 0][j] = (half_t)va.x; Vt[s + 1][j] = (half_t)va.y;
      Vt[s + 2][j] = (half_t)va.z; Vt[s + 3][j] = (half_t)va.w;
      Vt[s + 4][j] = (half_t)vb.x; Vt[s + 5][j] = (half_t)vb.y;
      Vt[s + 6][j] = (half_t)vb.z; Vt[s + 7][j] = (half_t)vb.w;
    }
    __syncthreads();
    f32x4 sAcc[8];
#pragma unroll
    for (int n = 0; n < 8; ++n) sAcc[n] = f32x4{0.f, 0.f, 0.f, 0.f};
#pragma unroll
    for (int n = 0; n < 8; ++n) {
      f16x8 kb0 = *(const f16x8*)&Ks[n * 16 + mrow][quad * 8];
      f16x8 kb1 = *(const f16x8*)&Ks[n * 16 + mrow][32 + quad * 8];
      sAcc[n] = __builtin_amdgcn_mfma_f32_16x16x32_f16(qa0, kb0, sAcc[n], 0, 0, 0);
      sAcc[n] = __builtin_amdgcn_mfma_f32_16x16x32_f16(qa1, kb1, sAcc[n], 0, 0, 0);
    }
    float p[8][4];
    float mx[4] = {-1e30f, -1e30f, -1e30f, -1e30f};
#pragma unroll
    for (int n = 0; n < 8; ++n)
#pragma unroll
      for (int r = 0; r < 4; ++r) {
        float v = sAcc[n][r] * 0.125f;
        p[n][r] = v;
        mx[r] = fmaxf(mx[r], v);
      }
#pragma unroll
    for (int off = 8; off > 0; off >>= 1)
#pragma unroll
      for (int r = 0; r < 4; ++r) mx[r] = fmaxf(mx[r], __shfl_xor(mx[r], off, 64));
    float corr[4], ls[4];
#pragma unroll
    for (int r = 0; r < 4; ++r) {
      float mn = fmaxf(m[r], mx[r]);
      corr[r] = __expf(m[r] - mn);
      m[r] = mn;
      ls[r] = 0.f;
    }
#pragma unroll
    for (int n = 0; n < 8; ++n)
#pragma unroll
      for (int r = 0; r < 4; ++r) {
        float e = __expf(p[n][r] - m[r]);
        p[n][r] = e;
        ls[r] += e;
      }
#pragma unroll
    for (int off = 8; off > 0; off >>= 1)
#pragma unroll
      for (int r = 0; r < 4; ++r) ls[r] += __shfl_xor(ls[r], off, 64);
#pragma unroll
    for (int r = 0; r < 4; ++r) l[r] = l[r] * corr[r] + ls[r];
#pragma unroll
    for (int n = 0; n < 4; ++n) {
      o[n][0] *= corr[0]; o[n][1] *= corr[1]; o[n][2] *= corr[2]; o[n][3] *= corr[3];
    }
#pragma unroll
    for (int n = 0; n < 8; ++n)
#pragma unroll
      for (int r = 0; r < 4; ++r)
        Ps[wave][quad * 4 + r][n * 16 + mrow] = (half_t)p[n][r];
    __syncthreads();
    f16x8 pa0 = *(const f16x8*)&Ps[wave][mrow][0 * 32 + quad * 8];
    f16x8 pa1 = *(const f16x8*)&Ps[wave][mrow][1 * 32 + quad * 8];
    f16x8 pa2 = *(const f16x8*)&Ps[wave][mrow][2 * 32 + quad * 8];
    f16x8 pa3 = *(const f16x8*)&Ps[wave][mrow][3 * 32 + quad * 8];
#pragma unroll
    for (int n = 0; n < 4; ++n) {
      f16x8 vb0 = *(const f16x8*)&Vt[n * 16 + mrow][0 * 32 + quad * 8];
      f16x8 vb1 = *(const f16x8*)&Vt[n * 16 + mrow][1 * 32 + quad * 8];
      f16x8 vb2 = *(const f16x8*)&Vt[n * 16 + mrow][2 * 32 + quad * 8];
      f16x8 vb3 = *(const f16x8*)&Vt[n * 16 + mrow][3 * 32 + quad * 8];
      o[n] = __builtin_amdgcn_mfma_f32_16x16x32_f16(pa0, vb0, o[n], 0, 0, 0);
      o[n] = __builtin_amdgcn_mfma_f32_16x16x32_f16(pa1, vb1, o[n], 0, 0, 0);
      o[n] = __builtin_amdgcn_mfma_f32_16x16x32_f16(pa2, vb2, o[n], 0, 0, 0);
      o[n] = __builtin_amdgcn_mfma_f32_16x16x32_f16(pa3, vb3, o[n], 0, 0, 0);
    }
    __syncthreads();  // before next tile's staging overwrites Ks/Vt
  }
#pragma unroll
  for (int n = 0; n < 4; ++n)
#pragma unroll
    for (int r = 0; r < 4; ++r)
      ctx16[(size_t)(b * TT + q0 + wave * 16 + quad * 4 + r) * HH + hd * HDIM +
            n * 16 + mrow] = (half_t)(o[n][r] / l[r]);
}

// ---------------- mean pool over T ----------------
__global__ void mean_pool(const float* __restrict__ x, float* __restrict__ out) {
  int b = blockIdx.x, j = threadIdx.x;
  const float* p = x + (size_t)b * TT * HH + j;
  float s = 0.f;
  for (int t = 0; t < TT; ++t) s += p[(size_t)t * HH];
  out[b * HH + j] = s * (1.f / 512.f);
}

// ---------------- FC layers ----------------
__global__ void fc1_k(const float* __restrict__ pooled, const float* __restrict__ w,
                      const float* __restrict__ bias, float* __restrict__ hid) {
  int b = blockIdx.x, o = threadIdx.x;  // 128 threads
  const float* pp = pooled + b * HH;
  const float* wp = w + o * HH;
  float s = 0.f;
#pragma unroll 4
  for (int k = 0; k < HH; ++k) s += pp[k] * wp[k];
  hid[b * 128 + o] = fmaxf(s + bias[o], 0.f);
}

__global__ void fc2_k(const float* __restrict__ hid, const float* __restrict__ w,
                      const float* __restrict__ bias, float* __restrict__ out) {
  int t = threadIdx.x;  // 256 = 32 m x 8 c
  int mm = t >> 3, c = t & 7;
  const float* hp = hid + mm * 128;
  const float* wp = w + c * 128;
  float s = 0.f;
#pragma unroll 4
  for (int k = 0; k < 128; ++k) s += hp[k] * wp[k];
  out[mm * 8 + c] = s + bias[c];
}

extern "C" void kernel_launch(void* const* d_in, const int* in_sizes, int n_in,
                              void* d_out, int out_size, void* d_ws, size_t ws_size,
                              hipStream_t stream) {
  (void)in_sizes; (void)n_in; (void)out_size; (void)ws_size;
  const float* x    = (const float*)d_in[0];
  const float* Wih0 = (const float*)d_in[1];
  const float* Whh0 = (const float*)d_in[2];
  const float* bih0 = (const float*)d_in[3];
  const float* bhh0 = (const float*)d_in[4];
  const float* Wih1 = (const float*)d_in[5];
  const float* Whh1 = (const float*)d_in[6];
  const float* bih1 = (const float*)d_in[7];
  const float* bhh1 = (const float*)d_in[8];
  const float* gatW = (const float*)d_in[9];
  const float* gatA = (const float*)d_in[10];
  const float* lng  = (const float*)d_in[11];
  const float* lnb  = (const float*)d_in[12];
  const float* inw  = (const float*)d_in[13];
  const float* inb  = (const float*)d_in[14];
  const float* outw = (const float*)d_in[15];
  const float* outb = (const float*)d_in[16];
  const float* f1w  = (const float*)d_in[17];
  const float* f1b  = (const float*)d_in[18];
  const float* f2w  = (const float*)d_in[19];
  const float* f2b  = (const float*)d_in[20];
  float* out = (float*)d_out;
  float* ws = (float*)d_ws;

  // fp32 regions:
  float* XPA   = ws;                  // 16384*768: xp0 -> xp1 -> qkv
  float* G0    = ws + 12582912;       // gat_out (gru0 fp32 h never stored)
  float* G1    = G0 + 4194304;        // gru1-out (fp32, for ln_res)
  float* Yb    = G1 + 4194304;        // [f16 G0_16 | f16 G1_16] -> attn_out fp32
  float* HGAT  = Yb + 4194304;        // gat feats fp32 -> [f16 CTX16 | f16 Y16]
  float* GATWTf= HGAT + 4194304;
  float* FSRC  = GATWTf + 65536;
  float* FDST  = FSRC + 65536;
  float* POOL  = FDST + 65536;
  float* HIDb  = POOL + 8192;
  float* W16b  = HIDb + 4096;         // f16 weight pool (~1.1 MB)

  // f16 aliases (lifetimes verified against launch order):
  half_t* X16     = (half_t*)G1;                   // dead before gru1 writes G1
  half_t* G0_16   = (half_t*)Yb;                   // dead before attn_out write
  half_t* G1_16   = (half_t*)(Yb + 2097152);
  half_t* CTX16   = (half_t*)HGAT;                 // written after gat phase done
  half_t* Y16     = (half_t*)(HGAT + 2097152);
  half_t* GATWT16 = (half_t*)GATWTf;
  half_t* W16ih0  = (half_t*)W16b;
  half_t* W16ih1  = (half_t*)(W16b + 49152);
  half_t* W16in   = (half_t*)(W16b + 49152 + 98304);
  half_t* W16out  = (half_t*)(W16b + 49152 + 98304 + 98304);

  // 0. casts (weights once; x once)
  castk<<<2048, 256, 0, stream>>>(x, X16, 2097152);
  castk<<<96, 256, 0, stream>>>(Wih0, W16ih0, 98304);
  castk<<<192, 256, 0, stream>>>(Wih1, W16ih1, 196608);
  castk<<<192, 256, 0, stream>>>(inw, W16in, 196608);
  castk<<<64, 256, 0, stream>>>(outw, W16out, 65536);
  gat_wt<<<256, 256, 0, stream>>>(gatW, GATWT16);
  // 1. xp0 = x @ W_ih0^T + b_ih0   (MFMA f16)
  gemm_f16<<<dim3(12, 128), 256, 0, stream>>>(X16, W16ih0, bih0, XPA, 16384, 768, 128);
  // 2. GRU layer 0 (fp32 h not needed -> nullptr)
  gru_layer<<<32, 1024, 0, stream>>>(XPA, Whh0, bhh0, nullptr, G0_16);
  // 3. xp1 = g0 @ W_ih1^T + b_ih1
  gemm_f16<<<dim3(12, 128), 256, 0, stream>>>(G0_16, W16ih1, bih1, XPA, 16384, 768, 256);
  // 4. GRU layer 1
  gru_layer<<<32, 1024, 0, stream>>>(XPA, Whh1, bhh1, G1, G1_16);
  // 5. GAT per-head features + attention
  gemm_f16<<<dim3(4, 128), 256, 0, stream>>>(G1_16, GATWT16, nullptr, HGAT, 16384, 256, 256);
  gat_fsd<<<dim3(32, 4), 512, 0, stream>>>(HGAT, gatA, FSRC, FDST);
  gat_attn<<<dim3(8, 4, 32), 256, 0, stream>>>(HGAT, FSRC, FDST, G0);
  // 6. y = LN(g + gat_out) -> f16
  ln_res<<<4096, 256, 0, stream>>>(G1, G0, lng, lnb, Y16);
  // 7. MHA
  gemm_f16<<<dim3(12, 128), 256, 0, stream>>>(Y16, W16in, inb, XPA, 16384, 768, 256);
  mha_attn<<<dim3(8, 4, 32), 256, 0, stream>>>(XPA, CTX16);
  gemm_f16<<<dim3(4, 128), 256, 0, stream>>>(CTX16, W16out, outb, Yb, 16384, 256, 256);
  // 8. pool + FC head
  mean_pool<<<32, 256, 0, stream>>>(Yb, POOL);
  fc1_k<<<32, 128, 0, stream>>>(POOL, f1w, f1b, HIDb);
  fc2_k<<<1, 256, 0, stream>>>(HIDb, f2w, f2b, out);
}

// Round 9
// 1610.688 us; speedup vs baseline: 1.1471x; 1.1471x over previous
//
#include <hip/hip_runtime.h>
#include <math.h>

// Problem constants
#define BB 32
#define TT 512
#define INF_ 128
#define HH 256
#define H3 768
#define NHEADS 4
#define HDIM 64

typedef _Float16 half_t;
typedef half_t half2_t __attribute__((ext_vector_type(2)));
typedef half_t half4_t __attribute__((ext_vector_type(4)));
typedef half_t f16x8 __attribute__((ext_vector_type(8)));
typedef float f32x4 __attribute__((ext_vector_type(4)));

#if defined(__has_builtin)
#if __has_builtin(__builtin_amdgcn_fdot2)
#define FDOT2(a, b, c) __builtin_amdgcn_fdot2((a), (b), (c), false)
#endif
#endif
#ifndef FDOT2
#define FDOT2(a, b, c) fmaf((float)(a).x, (float)(b).x, fmaf((float)(a).y, (float)(b).y, (c)))
#endif

#define BCH(x) __builtin_bit_cast(half2_t, x)

// ---------------- wave helpers (wave = 64 on CDNA) ----------------
__device__ __forceinline__ float wsum(float v) {
#pragma unroll
  for (int o = 32; o > 0; o >>= 1) v += __shfl_xor(v, o, 64);
  return v;
}
__device__ __forceinline__ float wmax(float v) {
#pragma unroll
  for (int o = 32; o > 0; o >>= 1) v = fmaxf(v, __shfl_xor(v, o, 64));
  return v;
}

// ---------------- fp32 -> f16 cast (n % 1024 == 0) ----------------
__global__ void castk(const float* __restrict__ s, half_t* __restrict__ d, int n) {
  int i = (blockIdx.x * 256 + threadIdx.x) * 4;
  if (i < n) {
    float4 v = *(const float4*)(s + i);
    half4_t o = {(half_t)v.x, (half_t)v.y, (half_t)v.z, (half_t)v.w};
    *(half4_t*)(d + i) = o;
  }
}

// ---------------- MFMA f16 GEMM: C = A[M,K] * B[N,K]^T + bias -------------
// Output: fp32 to C, or f16 to C16 (if C16 != nullptr). f16 output is
// numerics-neutral for consumers that round to f16 anyway (mha/gat staging).
__global__ __launch_bounds__(256) void gemm_f16(
    const half_t* __restrict__ A, const half_t* __restrict__ B,
    const float* __restrict__ bias, float* __restrict__ C,
    half_t* __restrict__ C16, int M, int N, int K) {
  __shared__ __align__(16) half_t As[128][40];
  __shared__ __align__(16) half_t Bs[64][40];
  const int tid = threadIdx.x;
  const int wave = tid >> 6, lane = tid & 63;
  const int m0 = blockIdx.y * 128, n0 = blockIdx.x * 64;
  const int mrow = lane & 15, quad = lane >> 4;
  f32x4 acc00 = {0.f, 0.f, 0.f, 0.f}, acc01 = acc00, acc02 = acc00, acc03 = acc00;
  f32x4 acc10 = acc00, acc11 = acc00, acc12 = acc00, acc13 = acc00;
  for (int k0 = 0; k0 < K; k0 += 32) {
    __syncthreads();  // previous iter's fragments consumed
#pragma unroll
    for (int u = 0; u < 2; ++u) {  // stage A: 128 rows x 32 halfs
      int idx = tid + u * 256;
      int row = idx >> 2, seg = idx & 3;
      *(f16x8*)&As[row][seg * 8] =
          *(const f16x8*)&A[(size_t)(m0 + row) * K + k0 + seg * 8];
    }
    {  // stage B: 64 rows x 32 halfs
      int row = tid >> 2, seg = tid & 3;
      *(f16x8*)&Bs[row][seg * 8] =
          *(const f16x8*)&B[(size_t)(n0 + row) * K + k0 + seg * 8];
    }
    __syncthreads();
    f16x8 af0 = *(const f16x8*)&As[wave * 32 + mrow][quad * 8];
    f16x8 af1 = *(const f16x8*)&As[wave * 32 + 16 + mrow][quad * 8];
    f16x8 bf0 = *(const f16x8*)&Bs[mrow][quad * 8];
    f16x8 bf1 = *(const f16x8*)&Bs[16 + mrow][quad * 8];
    f16x8 bf2 = *(const f16x8*)&Bs[32 + mrow][quad * 8];
    f16x8 bf3 = *(const f16x8*)&Bs[48 + mrow][quad * 8];
    acc00 = __builtin_amdgcn_mfma_f32_16x16x32_f16(af0, bf0, acc00, 0, 0, 0);
    acc01 = __builtin_amdgcn_mfma_f32_16x16x32_f16(af0, bf1, acc01, 0, 0, 0);
    acc02 = __builtin_amdgcn_mfma_f32_16x16x32_f16(af0, bf2, acc02, 0, 0, 0);
    acc03 = __builtin_amdgcn_mfma_f32_16x16x32_f16(af0, bf3, acc03, 0, 0, 0);
    acc10 = __builtin_amdgcn_mfma_f32_16x16x32_f16(af1, bf0, acc10, 0, 0, 0);
    acc11 = __builtin_amdgcn_mfma_f32_16x16x32_f16(af1, bf1, acc11, 0, 0, 0);
    acc12 = __builtin_amdgcn_mfma_f32_16x16x32_f16(af1, bf2, acc12, 0, 0, 0);
    acc13 = __builtin_amdgcn_mfma_f32_16x16x32_f16(af1, bf3, acc13, 0, 0, 0);
  }
  float bv0 = bias ? bias[n0 + mrow] : 0.f;
  float bv1 = bias ? bias[n0 + 16 + mrow] : 0.f;
  float bv2 = bias ? bias[n0 + 32 + mrow] : 0.f;
  float bv3 = bias ? bias[n0 + 48 + mrow] : 0.f;
  const int rb = m0 + wave * 32 + quad * 4;
  if (C16) {
#pragma unroll
    for (int r = 0; r < 4; ++r) {
      half_t* c0 = C16 + (size_t)(rb + r) * N + n0;
      c0[mrow] = (half_t)(acc00[r] + bv0);
      c0[16 + mrow] = (half_t)(acc01[r] + bv1);
      c0[32 + mrow] = (half_t)(acc02[r] + bv2);
      c0[48 + mrow] = (half_t)(acc03[r] + bv3);
      half_t* c1 = C16 + (size_t)(rb + 16 + r) * N + n0;
      c1[mrow] = (half_t)(acc10[r] + bv0);
      c1[16 + mrow] = (half_t)(acc11[r] + bv1);
      c1[32 + mrow] = (half_t)(acc12[r] + bv2);
      c1[48 + mrow] = (half_t)(acc13[r] + bv3);
    }
  } else {
#pragma unroll
    for (int r = 0; r < 4; ++r) {
      float* c0 = C + (size_t)(rb + r) * N + n0;
      c0[mrow] = acc00[r] + bv0;
      c0[16 + mrow] = acc01[r] + bv1;
      c0[32 + mrow] = acc02[r] + bv2;
      c0[48 + mrow] = acc03[r] + bv3;
      float* c1 = C + (size_t)(rb + 16 + r) * N + n0;
      c1[mrow] = acc10[r] + bv0;
      c1[16 + mrow] = acc11[r] + bv1;
      c1[32 + mrow] = acc12[r] + bv2;
      c1[48 + mrow] = acc13[r] + bv3;
    }
  }
}

// ---------------- GRU recurrence: all-register weights (R6, best=670us) ---
// R5-R7 established: the recurrence is FDOT2-issue-rate-bound (~2100 VALU
// cyc/step regardless of weight placement: R14 LDS-stream 693, R6 all-reg
// 670, R7 4-way-split 776). v_dot2_f32_f16 appears ~quarter-rate, so any
// FDOT2 restructure with the same lane-work lands at the same floor; MFMA
// escape attempts (R1-R4) all hit the operand-storage wall. Keeping R6.
#define LDW(g, p, a, b, i)                             \
  {                                                    \
    float4 v = (p)[i];                                 \
    g##a = half2_t{(half_t)v.x, (half_t)v.y};          \
    g##b = half2_t{(half_t)v.z, (half_t)v.w};          \
  }
#define LDW32(g, p)                                                        \
  LDW(g, p, 0, 1, 0) LDW(g, p, 2, 3, 1) LDW(g, p, 4, 5, 2)                 \
  LDW(g, p, 6, 7, 3) LDW(g, p, 8, 9, 4) LDW(g, p, 10, 11, 5)               \
  LDW(g, p, 12, 13, 6) LDW(g, p, 14, 15, 7) LDW(g, p, 16, 17, 8)           \
  LDW(g, p, 18, 19, 9) LDW(g, p, 20, 21, 10) LDW(g, p, 22, 23, 11)         \
  LDW(g, p, 24, 25, 12) LDW(g, p, 26, 27, 13) LDW(g, p, 28, 29, 14)        \
  LDW(g, p, 30, 31, 15) LDW(g, p, 32, 33, 16) LDW(g, p, 34, 35, 17)        \
  LDW(g, p, 36, 37, 18) LDW(g, p, 38, 39, 19) LDW(g, p, 40, 41, 20)        \
  LDW(g, p, 42, 43, 21) LDW(g, p, 44, 45, 22) LDW(g, p, 46, 47, 23)        \
  LDW(g, p, 48, 49, 24) LDW(g, p, 50, 51, 25) LDW(g, p, 52, 53, 26)        \
  LDW(g, p, 54, 55, 27) LDW(g, p, 56, 57, 28) LDW(g, p, 58, 59, 29)        \
  LDW(g, p, 60, 61, 30) LDW(g, p, 62, 63, 31)

#define DECL64(g)                                                          \
  half2_t g##0, g##1, g##2, g##3, g##4, g##5, g##6, g##7, g##8, g##9,      \
      g##10, g##11, g##12, g##13, g##14, g##15, g##16, g##17, g##18,       \
      g##19, g##20, g##21, g##22, g##23, g##24, g##25, g##26, g##27,       \
      g##28, g##29, g##30, g##31, g##32, g##33, g##34, g##35, g##36,       \
      g##37, g##38, g##39, g##40, g##41, g##42, g##43, g##44, g##45,       \
      g##46, g##47, g##48, g##49, g##50, g##51, g##52, g##53, g##54,       \
      g##55, g##56, g##57, g##58, g##59, g##60, g##61, g##62, g##63;

// one 8-dim chunk: r,z,n all from registers
#define CHR(c8, a0, a1, a2, a3)                                            \
  {                                                                        \
    float4 v = hp4[c8];                                                    \
    half2_t t0 = __builtin_bit_cast(half2_t, v.x);                         \
    half2_t t1 = __builtin_bit_cast(half2_t, v.y);                         \
    half2_t t2 = __builtin_bit_cast(half2_t, v.z);                         \
    half2_t t3 = __builtin_bit_cast(half2_t, v.w);                         \
    ar = FDOT2(wr##a0, t0, ar); az = FDOT2(wz##a0, t0, az); an = FDOT2(wn##a0, t0, an); \
    ar = FDOT2(wr##a1, t1, ar); az = FDOT2(wz##a1, t1, az); an = FDOT2(wn##a1, t1, an); \
    ar = FDOT2(wr##a2, t2, ar); az = FDOT2(wz##a2, t2, az); an = FDOT2(wn##a2, t2, an); \
    ar = FDOT2(wr##a3, t3, ar); az = FDOT2(wz##a3, t3, az); an = FDOT2(wn##a3, t3, an); \
  }

__global__ __launch_bounds__(512, 2) void gru_layer(
    const float* __restrict__ xp, const float* __restrict__ Whh,
    const float* __restrict__ bhh, float* __restrict__ out,
    half_t* __restrict__ out16) {
  __shared__ __align__(16) half_t hs[2][2][144];
  const int tid = threadIdx.x;
  const int kh = tid & 1, j = tid >> 1;
  const int b = blockIdx.x;
  const bool wf32 = (out != nullptr);  // uniform: layer 0 skips fp32 h-store
  DECL64(wr)
  DECL64(wz)
  DECL64(wn)
  {
    const float4* pr = (const float4*)(Whh + (size_t)j * HH + kh * 128);
    const float4* pz = (const float4*)(Whh + (size_t)(HH + j) * HH + kh * 128);
    const float4* pn = (const float4*)(Whh + (size_t)(2 * HH + j) * HH + kh * 128);
    LDW32(wr, pr)
    LDW32(wz, pz)
    LDW32(wn, pn)
  }
  const float br = bhh[j], bz = bhh[HH + j], bn = bhh[2 * HH + j];
  for (int i = tid; i < 288; i += 512) ((unsigned*)hs)[i] = 0u;
  __syncthreads();
  float hprev = 0.f;
  const float* xrow = xp + (size_t)b * TT * H3;
  float* orow = out + (size_t)b * TT * HH;
  half_t* orow16 = out16 + (size_t)b * TT * HH;
  for (int t = 0; t < TT; ++t) {
    float xr = xrow[j], xz = xrow[HH + j], xn = xrow[2 * HH + j];
    const float4* hp4 = (const float4*)&hs[t & 1][kh][0];
    float ar = 0.f, az = 0.f, an = 0.f;
    CHR(0, 0, 1, 2, 3)
    CHR(1, 4, 5, 6, 7)
    CHR(2, 8, 9, 10, 11)
    CHR(3, 12, 13, 14, 15)
    CHR(4, 16, 17, 18, 19)
    CHR(5, 20, 21, 22, 23)
    CHR(6, 24, 25, 26, 27)
    CHR(7, 28, 29, 30, 31)
    CHR(8, 32, 33, 34, 35)
    CHR(9, 36, 37, 38, 39)
    CHR(10, 40, 41, 42, 43)
    CHR(11, 44, 45, 46, 47)
    CHR(12, 48, 49, 50, 51)
    CHR(13, 52, 53, 54, 55)
    CHR(14, 56, 57, 58, 59)
    CHR(15, 60, 61, 62, 63)
    ar += __shfl_xor(ar, 1);
    az += __shfl_xor(az, 1);
    an += __shfl_xor(an, 1);
    float rg = 1.f / (1.f + __expf(-(xr + ar + br)));
    float zg = 1.f / (1.f + __expf(-(xz + az + bz)));
    float ng = 2.f / (1.f + __expf(-2.f * (xn + rg * (an + bn)))) - 1.f;  // tanh, inf-safe
    float hnew = (1.f - zg) * ng + zg * hprev;
    hprev = hnew;
    float hpart = __shfl_xor(hnew, 2);  // lane (kh=0, even j) gets h_{j+1}
    if ((tid & 3) == 0) {               // kh==0 && j even: one b32 packed write
      half2_t pk;
      pk.x = (half_t)hnew;
      pk.y = (half_t)hpart;
      *(half2_t*)&hs[(t + 1) & 1][j >> 7][j & 127] = pk;
    }
    if (kh == 0) {
      orow16[j] = (half_t)hnew;
      if (wf32) orow[j] = hnew;
    }
    __syncthreads();
    xrow += H3;
    orow += HH;
    orow16 += HH;
  }
}

// ---------------- gat_W transpose -> f16: [4,256,64] -> [256 cols][256 k] --
__global__ void gat_wt(const float* __restrict__ W, half_t* __restrict__ Wt) {
  int idx = blockIdx.x * 256 + threadIdx.x;  // [0, 65536)
  int col = idx >> 8, k = idx & 255;
  Wt[idx] = (half_t)W[((size_t)((col >> 6) * HH + k)) * HDIM + (col & 63)];
}

// ---------------- GAT f_src/f_dst (f16 features) ----------------
__global__ void gat_fsd(const half_t* __restrict__ hgat, const float* __restrict__ a,
                        float* __restrict__ fsrc, float* __restrict__ fdst) {
  int b = blockIdx.x, hd = blockIdx.y, t = threadIdx.x;  // block 512
  const half_t* hp = hgat + ((size_t)(b * TT + t)) * HH + hd * HDIM;
  const float* ap = a + hd * 2 * HDIM;
  float fs = 0.f, fd = 0.f;
#pragma unroll
  for (int s8 = 0; s8 < 8; ++s8) {
    f16x8 hv8 = *(const f16x8*)(hp + s8 * 8);
#pragma unroll
    for (int i = 0; i < 8; ++i) {
      float hv = (float)hv8[i];
      fs += hv * ap[s8 * 8 + i];
      fd += hv * ap[HDIM + s8 * 8 + i];
    }
  }
  fsrc[(b * NHEADS + hd) * TT + t] = fs;
  fdst[(b * NHEADS + hd) * TT + t] = fd;
}

// ---------------- GAT flash attention (MFMA PV, f16 features) -------------
__global__ __launch_bounds__(256) void gat_attn(
    const half_t* __restrict__ hgat, const float* __restrict__ fsrc,
    const float* __restrict__ fdst, float* __restrict__ out) {
  __shared__ __align__(16) half_t Htt[64][136];     // H^T per j-tile
  __shared__ __align__(16) half_t Ps[4][16][136];   // per-wave P (f16)
  __shared__ __align__(16) float fd[128];
  const int tid = threadIdx.x, wave = tid >> 6, lane = tid & 63;
  const int mrow = lane & 15, quad = lane >> 4;
  const int hd = blockIdx.y, b = blockIdx.z;
  const int q0 = blockIdx.x * 64;
  const float fi = fsrc[(size_t)(b * NHEADS + hd) * TT + q0 + wave * 16 + mrow];
  const float* fdp = fdst + (size_t)(b * NHEADS + hd) * TT;
  float m = -1e30f, l = 0.f;
  f32x4 o[4];
#pragma unroll
  for (int n = 0; n < 4; ++n) o[n] = f32x4{0.f, 0.f, 0.f, 0.f};
  for (int jt = 0; jt < TT; jt += 128) {
#pragma unroll
    for (int u = 0; u < 4; ++u) {  // stage H^T: Htt[d][j] (f16 source)
      int idx = tid + u * 256;
      int j = idx >> 3, s = (idx & 7) * 8;
      f16x8 hv = *(const f16x8*)&hgat[(size_t)(b * TT + jt + j) * HH + hd * HDIM + s];
      Htt[s + 0][j] = hv[0]; Htt[s + 1][j] = hv[1];
      Htt[s + 2][j] = hv[2]; Htt[s + 3][j] = hv[3];
      Htt[s + 4][j] = hv[4]; Htt[s + 5][j] = hv[5];
      Htt[s + 6][j] = hv[6]; Htt[s + 7][j] = hv[7];
    }
    if (tid < 32) *(float4*)&fd[tid * 4] = *(const float4*)&fdp[jt + tid * 4];
    __syncthreads();
    float p[32];
    float mx = -1e30f;
#pragma unroll
    for (int g = 0; g < 8; ++g) {
      float4 f4 = *(const float4*)&fd[quad * 32 + g * 4];
      float e0 = fi + f4.x; e0 = (e0 > 0.f) ? e0 : 0.2f * e0;
      float e1 = fi + f4.y; e1 = (e1 > 0.f) ? e1 : 0.2f * e1;
      float e2 = fi + f4.z; e2 = (e2 > 0.f) ? e2 : 0.2f * e2;
      float e3 = fi + f4.w; e3 = (e3 > 0.f) ? e3 : 0.2f * e3;
      p[g * 4 + 0] = e0; p[g * 4 + 1] = e1; p[g * 4 + 2] = e2; p[g * 4 + 3] = e3;
      mx = fmaxf(mx, fmaxf(fmaxf(e0, e1), fmaxf(e2, e3)));
    }
    mx = fmaxf(mx, __shfl_xor(mx, 16, 64));  // reduce over the 4 j-groups
    mx = fmaxf(mx, __shfl_xor(mx, 32, 64));
    float mn = fmaxf(m, mx);
    float corr = __expf(m - mn);
    m = mn;
    float ls = 0.f;
#pragma unroll
    for (int i = 0; i < 32; ++i) { p[i] = __expf(p[i] - mn); ls += p[i]; }
    ls += __shfl_xor(ls, 16, 64);
    ls += __shfl_xor(ls, 32, 64);
    l = l * corr + ls;
    float cr[4];  // corr for PV acc rows q' = quad*4+r (held by lane q')
#pragma unroll
    for (int r = 0; r < 4; ++r) cr[r] = __shfl(corr, quad * 4 + r, 64);
#pragma unroll
    for (int n = 0; n < 4; ++n) {
      o[n][0] *= cr[0]; o[n][1] *= cr[1]; o[n][2] *= cr[2]; o[n][3] *= cr[3];
    }
#pragma unroll
    for (int s8 = 0; s8 < 4; ++s8) {  // P f16 -> LDS [q][j]
      f16x8 pkv = {(half_t)p[s8 * 8 + 0], (half_t)p[s8 * 8 + 1],
                   (half_t)p[s8 * 8 + 2], (half_t)p[s8 * 8 + 3],
                   (half_t)p[s8 * 8 + 4], (half_t)p[s8 * 8 + 5],
                   (half_t)p[s8 * 8 + 6], (half_t)p[s8 * 8 + 7]};
      *(f16x8*)&Ps[wave][mrow][quad * 32 + s8 * 8] = pkv;
    }
    __syncthreads();
    f16x8 pa0 = *(const f16x8*)&Ps[wave][mrow][0 * 32 + quad * 8];
    f16x8 pa1 = *(const f16x8*)&Ps[wave][mrow][1 * 32 + quad * 8];
    f16x8 pa2 = *(const f16x8*)&Ps[wave][mrow][2 * 32 + quad * 8];
    f16x8 pa3 = *(const f16x8*)&Ps[wave][mrow][3 * 32 + quad * 8];
#pragma unroll
    for (int n = 0; n < 4; ++n) {
      f16x8 vb0 = *(const f16x8*)&Htt[n * 16 + mrow][0 * 32 + quad * 8];
      f16x8 vb1 = *(const f16x8*)&Htt[n * 16 + mrow][1 * 32 + quad * 8];
      f16x8 vb2 = *(const f16x8*)&Htt[n * 16 + mrow][2 * 32 + quad * 8];
      f16x8 vb3 = *(const f16x8*)&Htt[n * 16 + mrow][3 * 32 + quad * 8];
      o[n] = __builtin_amdgcn_mfma_f32_16x16x32_f16(pa0, vb0, o[n], 0, 0, 0);
      o[n] = __builtin_amdgcn_mfma_f32_16x16x32_f16(pa1, vb1, o[n], 0, 0, 0);
      o[n] = __builtin_amdgcn_mfma_f32_16x16x32_f16(pa2, vb2, o[n], 0, 0, 0);
      o[n] = __builtin_amdgcn_mfma_f32_16x16x32_f16(pa3, vb3, o[n], 0, 0, 0);
    }
    __syncthreads();  // before next tile's staging overwrites Htt
  }
  float lr[4];
#pragma unroll
  for (int r = 0; r < 4; ++r) lr[r] = __shfl(l, quad * 4 + r, 64);
#pragma unroll
  for (int n = 0; n < 4; ++n)
#pragma unroll
    for (int r = 0; r < 4; ++r)
      out[(size_t)(b * TT + q0 + wave * 16 + quad * 4 + r) * HH + hd * HDIM +
          n * 16 + mrow] = o[n][r] / lr[r];
}

// ---------------- residual + LayerNorm (f16 output for MFMA GEMM) ---------
__global__ __launch_bounds__(256) void ln_res(
    const float* __restrict__ g, const float* __restrict__ gat,
    const float* __restrict__ gamma, const float* __restrict__ beta,
    half_t* __restrict__ y16) {
  int wave = threadIdx.x >> 6, lane = threadIdx.x & 63;
  size_t n = (size_t)blockIdx.x * 4 + wave;
  float4 v = ((const float4*)(g + n * HH))[lane];
  float4 w = ((const float4*)(gat + n * HH))[lane];
  v.x += w.x; v.y += w.y; v.z += w.z; v.w += w.w;
  float mu = wsum(v.x + v.y + v.z + v.w) * (1.f / 256.f);
  float dx = v.x - mu, dy = v.y - mu, dz = v.z - mu, dw = v.w - mu;
  float var = wsum(dx * dx + dy * dy + dz * dz + dw * dw) * (1.f / 256.f);
  float rstd = rsqrtf(var + 1e-5f);
  float4 gm = ((const float4*)gamma)[lane];
  float4 bt = ((const float4*)beta)[lane];
  half4_t o = {(half_t)(dx * rstd * gm.x + bt.x), (half_t)(dy * rstd * gm.y + bt.y),
               (half_t)(dz * rstd * gm.z + bt.z), (half_t)(dw * rstd * gm.w + bt.w)};
  ((half4_t*)(y16 + n * HH))[lane] = o;
}

// ---------------- MHA flash attention (MFMA QK + PV, f16 qkv input) -------
__global__ __launch_bounds__(256) void mha_attn(const half_t* __restrict__ qkv,
                                                half_t* __restrict__ ctx16) {
  __shared__ __align__(16) half_t Qs[64][72];
  __shared__ __align__(16) half_t Ks[128][72];
  __shared__ __align__(16) half_t Vt[64][136];
  __shared__ __align__(16) half_t Ps[4][16][136];
  const int tid = threadIdx.x, wave = tid >> 6, lane = tid & 63;
  const int mrow = lane & 15, quad = lane >> 4;
  const int hd = blockIdx.y, b = blockIdx.z;
  const int q0 = blockIdx.x * 64;
  {  // stage Q: 64 q x 64 d (f16 source)
    int r = tid >> 2, s = (tid & 3) * 16;
    const half_t* src = qkv + (size_t)(b * TT + q0 + r) * H3 + hd * HDIM + s;
    *(f16x8*)&Qs[r][s] = *(const f16x8*)src;
    *(f16x8*)&Qs[r][s + 8] = *(const f16x8*)(src + 8);
  }
  __syncthreads();
  f16x8 qa0 = *(const f16x8*)&Qs[wave * 16 + mrow][quad * 8];
  f16x8 qa1 = *(const f16x8*)&Qs[wave * 16 + mrow][32 + quad * 8];
  float m[4] = {-1e30f, -1e30f, -1e30f, -1e30f};
  float l[4] = {0.f, 0.f, 0.f, 0.f};
  f32x4 o[4];
#pragma unroll
  for (int n = 0; n < 4; ++n) o[n] = f32x4{0.f, 0.f, 0.f, 0.f};
  for (int jt = 0; jt < TT; jt += 128) {
#pragma unroll
    for (int u = 0; u < 4; ++u) {  // stage K [j][d] and V^T [d][j]
      int idx = tid + u * 256;
      int j = idx >> 3, s = (idx & 7) * 8;
      const half_t* kp = qkv + (size_t)(b * TT + jt + j) * H3 + HH + hd * HDIM + s;
      *(f16x8*)&Ks[j][s] = *(const f16x8*)kp;
      f16x8 vv = *(const f16x8*)(kp + HH);
      Vt[s + 0][j] = vv[0]; Vt[s + 1][j] = vv[1];
      Vt[s + 2][j] = vv[2]; Vt[s + 3][j] = vv[3];
      Vt[s + 4][j] = vv[4]; Vt[s + 5][j] = vv[5];
      Vt[s + 6][j] = vv[6]; Vt[s + 7][j] = vv[7];
    }
    __syncthreads();
    f32x4 sAcc[8];
#pragma unroll
    for (int n = 0; n < 8; ++n) sAcc[n] = f32x4{0.f, 0.f, 0.f, 0.f};
#pragma unroll
    for (int n = 0; n < 8; ++n) {
      f16x8 kb0 = *(const f16x8*)&Ks[n * 16 + mrow][quad * 8];
      f16x8 kb1 = *(const f16x8*)&Ks[n * 16 + mrow][32 + quad * 8];
      sAcc[n] = __builtin_amdgcn_mfma_f32_16x16x32_f16(qa0, kb0, sAcc[n], 0, 0, 0);
      sAcc[n] = __builtin_amdgcn_mfma_f32_16x16x32_f16(qa1, kb1, sAcc[n], 0, 0, 0);
    }
    float p[8][4];
    float mx[4] = {-1e30f, -1e30f, -1e30f, -1e30f};
#pragma unroll
    for (int n = 0; n < 8; ++n)
#pragma unroll
      for (int r = 0; r < 4; ++r) {
        float v = sAcc[n][r] * 0.125f;
        p[n][r] = v;
        mx[r] = fmaxf(mx[r], v);
      }
#pragma unroll
    for (int off = 8; off > 0; off >>= 1)
#pragma unroll
      for (int r = 0; r < 4; ++r) mx[r] = fmaxf(mx[r], __shfl_xor(mx[r], off, 64));
    float corr[4], ls[4];
#pragma unroll
    for (int r = 0; r < 4; ++r) {
      float mn = fmaxf(m[r], mx[r]);
      corr[r] = __expf(m[r] - mn);
      m[r] = mn;
      ls[r] = 0.f;
    }
#pragma unroll
    for (int n = 0; n < 8; ++n)
#pragma unroll
      for (int r = 0; r < 4; ++r) {
        float e = __expf(p[n][r] - m[r]);
        p[n][r] = e;
        ls[r] += e;
      }
#pragma unroll
    for (int off = 8; off > 0; off >>= 1)
#pragma unroll
      for (int r = 0; r < 4; ++r) ls[r] += __shfl_xor(ls[r], off, 64);
#pragma unroll
    for (int r = 0; r < 4; ++r) l[r] = l[r] * corr[r] + ls[r];
#pragma unroll
    for (int n = 0; n < 4; ++n) {
      o[n][0] *= corr[0]; o[n][1] *= corr[1]; o[n][2] *= corr[2]; o[n][3] *= corr[3];
    }
#pragma unroll
    for (int n = 0; n < 8; ++n)
#pragma unroll
      for (int r = 0; r < 4; ++r)
        Ps[wave][quad * 4 + r][n * 16 + mrow] = (half_t)p[n][r];
    __syncthreads();
    f16x8 pa0 = *(const f16x8*)&Ps[wave][mrow][0 * 32 + quad * 8];
    f16x8 pa1 = *(const f16x8*)&Ps[wave][mrow][1 * 32 + quad * 8];
    f16x8 pa2 = *(const f16x8*)&Ps[wave][mrow][2 * 32 + quad * 8];
    f16x8 pa3 = *(const f16x8*)&Ps[wave][mrow][3 * 32 + quad * 8];
#pragma unroll
    for (int n = 0; n < 4; ++n) {
      f16x8 vb0 = *(const f16x8*)&Vt[n * 16 + mrow][0 * 32 + quad * 8];
      f16x8 vb1 = *(const f16x8*)&Vt[n * 16 + mrow][1 * 32 + quad * 8];
      f16x8 vb2 = *(const f16x8*)&Vt[n * 16 + mrow][2 * 32 + quad * 8];
      f16x8 vb3 = *(const f16x8*)&Vt[n * 16 + mrow][3 * 32 + quad * 8];
      o[n] = __builtin_amdgcn_mfma_f32_16x16x32_f16(pa0, vb0, o[n], 0, 0, 0);
      o[n] = __builtin_amdgcn_mfma_f32_16x16x32_f16(pa1, vb1, o[n], 0, 0, 0);
      o[n] = __builtin_amdgcn_mfma_f32_16x16x32_f16(pa2, vb2, o[n], 0, 0, 0);
      o[n] = __builtin_amdgcn_mfma_f32_16x16x32_f16(pa3, vb3, o[n], 0, 0, 0);
    }
    __syncthreads();  // before next tile's staging overwrites Ks/Vt
  }
#pragma unroll
  for (int n = 0; n < 4; ++n)
#pragma unroll
    for (int r = 0; r < 4; ++r)
      ctx16[(size_t)(b * TT + q0 + wave * 16 + quad * 4 + r) * HH + hd * HDIM +
            n * 16 + mrow] = (half_t)(o[n][r] / l[r]);
}

// ---------------- mean pool over T (two-stage, parallel over T) -----------
__global__ void mp1(const float* __restrict__ x, float* __restrict__ part) {
  int b = blockIdx.x, p = blockIdx.y, j = threadIdx.x;  // 256 thr
  const float* src = x + ((size_t)b * TT + p * 32) * HH + j;
  float s = 0.f;
#pragma unroll 8
  for (int t = 0; t < 32; ++t) s += src[(size_t)t * HH];
  part[((size_t)b * 16 + p) * HH + j] = s;
}
__global__ void mp2(const float* __restrict__ part, float* __restrict__ out) {
  int b = blockIdx.x, j = threadIdx.x;  // 256 thr
  const float* pp = part + (size_t)b * 16 * HH + j;
  float s = 0.f;
#pragma unroll
  for (int p = 0; p < 16; ++p) s += pp[p * HH];
  out[b * HH + j] = s * (1.f / 512.f);
}

// ---------------- FC layers ----------------
__global__ void fc1_k(const float* __restrict__ pooled, const float* __restrict__ w,
                      const float* __restrict__ bias, float* __restrict__ hid) {
  int b = blockIdx.x, o = threadIdx.x;  // 128 threads
  const float* pp = pooled + b * HH;
  const float* wp = w + o * HH;
  float s = 0.f;
#pragma unroll 4
  for (int k = 0; k < HH; ++k) s += pp[k] * wp[k];
  hid[b * 128 + o] = fmaxf(s + bias[o], 0.f);
}

__global__ void fc2_k(const float* __restrict__ hid, const float* __restrict__ w,
                      const float* __restrict__ bias, float* __restrict__ out) {
  int t = threadIdx.x;  // 256 = 32 m x 8 c
  int mm = t >> 3, c = t & 7;
  const float* hp = hid + mm * 128;
  const float* wp = w + c * 128;
  float s = 0.f;
#pragma unroll 4
  for (int k = 0; k < 128; ++k) s += hp[k] * wp[k];
  out[mm * 8 + c] = s + bias[c];
}

extern "C" void kernel_launch(void* const* d_in, const int* in_sizes, int n_in,
                              void* d_out, int out_size, void* d_ws, size_t ws_size,
                              hipStream_t stream) {
  (void)in_sizes; (void)n_in; (void)out_size; (void)ws_size;
  const float* x    = (const float*)d_in[0];
  const float* Wih0 = (const float*)d_in[1];
  const float* Whh0 = (const float*)d_in[2];
  const float* bih0 = (const float*)d_in[3];
  const float* bhh0 = (const float*)d_in[4];
  const float* Wih1 = (const float*)d_in[5];
  const float* Whh1 = (const float*)d_in[6];
  const float* bih1 = (const float*)d_in[7];
  const float* bhh1 = (const float*)d_in[8];
  const float* gatW = (const float*)d_in[9];
  const float* gatA = (const float*)d_in[10];
  const float* lng  = (const float*)d_in[11];
  const float* lnb  = (const float*)d_in[12];
  const float* inw  = (const float*)d_in[13];
  const float* inb  = (const float*)d_in[14];
  const float* outw = (const float*)d_in[15];
  const float* outb = (const float*)d_in[16];
  const float* f1w  = (const float*)d_in[17];
  const float* f1b  = (const float*)d_in[18];
  const float* f2w  = (const float*)d_in[19];
  const float* f2b  = (const float*)d_in[20];
  float* out = (float*)d_out;
  float* ws = (float*)d_ws;

  // fp32 regions:
  float* XPA   = ws;                  // 16384*768: xp0 -> xp1 -> qkv(f16)
  float* G0    = ws + 12582912;       // gat_out fp32
  float* G1    = G0 + 4194304;        // gru1-out (fp32, for ln_res)
  float* Yb    = G1 + 4194304;        // [f16 G0_16 | f16 G1_16] -> attn_out fp32
  float* HGAT  = Yb + 4194304;        // [f16 HGAT16/CTX16 | f16 Y16]
  float* GATWTf= HGAT + 4194304;
  float* FSRC  = GATWTf + 65536;
  float* FDST  = FSRC + 65536;
  float* POOL  = FDST + 65536;
  float* HIDb  = POOL + 8192;
  float* W16b  = HIDb + 4096;         // f16 weight pool (~1.1 MB)

  // f16 aliases (lifetimes verified against launch order):
  half_t* X16     = (half_t*)G1;                   // dead before gru1 writes G1
  half_t* G0_16   = (half_t*)Yb;                   // dead before attn_out write
  half_t* G1_16   = (half_t*)(Yb + 2097152);
  half_t* HGAT16  = (half_t*)HGAT;                 // gat feats f16 (step 5)
  half_t* CTX16   = (half_t*)HGAT;                 // reused after gat phase done
  half_t* Y16     = (half_t*)(HGAT + 2097152);
  half_t* XPA16   = (half_t*)XPA;                  // qkv f16 (after gru phase)
  half_t* GATWT16 = (half_t*)GATWTf;
  half_t* W16ih0  = (half_t*)W16b;
  half_t* W16ih1  = (half_t*)(W16b + 49152);
  half_t* W16in   = (half_t*)(W16b + 49152 + 98304);
  half_t* W16out  = (half_t*)(W16b + 49152 + 98304 + 98304);
  // mean-pool partials [32][16][256] fp32: alias onto HGAT (CTX16 is dead
  // after the attn-out GEMM, which precedes mp1; next replay rewrites HGAT16
  // before any read).
  float* PART = HGAT;

  // 0. casts (weights once; x once)
  castk<<<2048, 256, 0, stream>>>(x, X16, 2097152);
  castk<<<96, 256, 0, stream>>>(Wih0, W16ih0, 98304);
  castk<<<192, 256, 0, stream>>>(Wih1, W16ih1, 196608);
  castk<<<192, 256, 0, stream>>>(inw, W16in, 196608);
  castk<<<64, 256, 0, stream>>>(outw, W16out, 65536);
  gat_wt<<<256, 256, 0, stream>>>(gatW, GATWT16);
  // 1. xp0 = x @ W_ih0^T + b_ih0   (MFMA f16, fp32 out for GRU)
  gemm_f16<<<dim3(12, 128), 256, 0, stream>>>(X16, W16ih0, bih0, XPA, nullptr, 16384, 768, 128);
  // 2. GRU layer 0 (fp32 h not needed -> nullptr)
  gru_layer<<<32, 512, 0, stream>>>(XPA, Whh0, bhh0, nullptr, G0_16);
  // 3. xp1 = g0 @ W_ih1^T + b_ih1
  gemm_f16<<<dim3(12, 128), 256, 0, stream>>>(G0_16, W16ih1, bih1, XPA, nullptr, 16384, 768, 256);
  // 4. GRU layer 1
  gru_layer<<<32, 512, 0, stream>>>(XPA, Whh1, bhh1, G1, G1_16);
  // 5. GAT per-head features (f16 out) + attention
  gemm_f16<<<dim3(4, 128), 256, 0, stream>>>(G1_16, GATWT16, nullptr, nullptr, HGAT16, 16384, 256, 256);
  gat_fsd<<<dim3(32, 4), 512, 0, stream>>>(HGAT16, gatA, FSRC, FDST);
  gat_attn<<<dim3(8, 4, 32), 256, 0, stream>>>(HGAT16, FSRC, FDST, G0);
  // 6. y = LN(g + gat_out) -> f16
  ln_res<<<4096, 256, 0, stream>>>(G1, G0, lng, lnb, Y16);
  // 7. MHA (qkv emitted f16 -- identical numerics to in-kernel rounding)
  gemm_f16<<<dim3(12, 128), 256, 0, stream>>>(Y16, W16in, inb, nullptr, XPA16, 16384, 768, 256);
  mha_attn<<<dim3(8, 4, 32), 256, 0, stream>>>(XPA16, CTX16);
  gemm_f16<<<dim3(4, 128), 256, 0, stream>>>(CTX16, W16out, outb, Yb, nullptr, 16384, 256, 256);
  // 8. pool + FC head
  mp1<<<dim3(32, 16), 256, 0, stream>>>(Yb, PART);
  mp2<<<32, 256, 0, stream>>>(PART, POOL);
  fc1_k<<<32, 128, 0, stream>>>(POOL, f1w, f1b, HIDb);
  fc2_k<<<1, 256, 0, stream>>>(HIDb, f2w, f2b, out);
}